// Round 1
// baseline (4127.607 us; speedup 1.0000x reference)
//
#include <hip/hip_runtime.h>
#include <hip/hip_bf16.h>
#include <stdint.h>

#define B_ 128
#define T_ 512
#define I_ 256
#define H_ 1024
#define O_ 256

typedef __attribute__((ext_vector_type(8))) short   bf16x8;
typedef __attribute__((ext_vector_type(4))) float   f32x4;
typedef __attribute__((ext_vector_type(4))) unsigned int u32x4;
typedef __attribute__((ext_vector_type(8))) unsigned short us8;

// ---- workspace layout (bytes) ----
#define WP_BYTES  (32*4*64*40*16)            // packed split-bf16 weights: 5,242,880
#define H2_BYTES  (2*B_*H_*2)                // double-buffered bf16 h: 524,288
#define CNT_BYTES (8*1024)                   // 8 per-batch-group barrier counters, 1KB apart

__device__ __forceinline__ unsigned short f2bf(float f) {
    union { float f; unsigned int u; } a; a.f = f;
    unsigned int u = a.u;
    return (unsigned short)((u + 0x7FFFu + ((u >> 16) & 1u)) >> 16);   // RNE
}
__device__ __forceinline__ float bf2f(unsigned short s) {
    union { unsigned int u; float f; } a; a.u = ((unsigned int)s) << 16; return a.f;
}

// ---------------- setup: pack W_hh|W_ih into per-lane MFMA B-fragment order, hi/lo split ----------------
// frag chunk addr: (((og*4 + wave)*64 + lane)*40 + n*2 + which) * 8 ushorts
// wave: kh = wave>>1 (K half), ch = wave&1 (col half). col = og*32 + ch*16 + (lane&15)
// src k = kh*640 + n*32 + (lane>>4)*8 + j ; k<1024 -> W_hh[col][k], else W_ih[col][k-1024]
__global__ void k_pack(const float* __restrict__ Whh, const float* __restrict__ Wih,
                       unsigned short* __restrict__ Wp) {
    int tid = blockIdx.x * 256 + threadIdx.x;
    if (tid >= 32*4*64*40) return;
    int q    = tid % 40;
    int lane = (tid / 40) % 64;
    int w    = (tid / (40*64)) % 4;
    int og   = tid / (40*64*4);
    int n = q >> 1, which = q & 1;
    int col = og*32 + (w & 1)*16 + (lane & 15);
    int sk  = (w >> 1)*640 + n*32 + ((lane >> 4) << 3);
    us8 out;
    #pragma unroll
    for (int j = 0; j < 8; ++j) {
        int k = sk + j;
        float wv = (k < H_) ? Whh[col*H_ + k] : Wih[col*I_ + (k - H_)];
        unsigned short hi = f2bf(wv);
        unsigned short v;
        if (which) v = f2bf(wv - bf2f(hi));
        else       v = hi;
        out[j] = v;
    }
    *reinterpret_cast<us8*>(Wp + (size_t)tid * 8) = out;
}

// ---------------- setup: h0 (bf16) + barrier counters ----------------
__global__ void k_init(const float* __restrict__ hid, unsigned short* __restrict__ h2,
                       unsigned int* __restrict__ cnt) {
    int i = blockIdx.x * 256 + threadIdx.x;
    if (i < B_*H_) h2[i] = f2bf(hid[i]);
    if (i < 8) cnt[i * 256] = 0u;
}

// ---------------- main persistent RNN kernel (cooperative) ----------------
#define MF(a, b, c) __builtin_amdgcn_mfma_f32_16x16x32_bf16((a), (b), (c), 0, 0, 0)

__launch_bounds__(256, 1)
__global__ void k_rnn(const float* __restrict__ x, const unsigned short* __restrict__ Wp,
                      unsigned short* __restrict__ h2, unsigned int* __restrict__ cnt,
                      const float* __restrict__ bih, const float* __restrict__ bhh,
                      float* __restrict__ outh) {
    const int bg   = blockIdx.x & 7;    // batch group -> XCD affinity
    const int og   = blockIdx.x >> 3;   // 0..31 col group
    const int tid  = threadIdx.x;
    const int wv   = tid >> 6;          // wave 0..3
    const int lane = tid & 63;
    const int kh   = wv >> 1;           // K half
    const int ch   = wv & 1;            // col half
    const int b0   = bg * 16;
    const int colg = og*32 + ch*16 + (lane & 15);
    const int rowa = lane & 15;         // A-fragment row (batch within tile)
    const int kgrp = lane >> 4;         // 0..3

    const int prow = tid >> 4;          // x-prefetch row 0..15
    const int pi0  = (tid & 15) * 16;   // x-prefetch col base (floats)

    __shared__ unsigned short xlds[2][16 * 256];   // bf16 x tile, swizzled, double buffered
    __shared__ float red[2][64][4];                // K-half reduction buffer

    // ---- B fragments resident in VGPRs for whole kernel ----
    bf16x8 bw[40];
    {
        const bf16x8* wp = reinterpret_cast<const bf16x8*>(Wp) + (size_t)((og*4 + wv)*64 + lane) * 40;
        #pragma unroll
        for (int m = 0; m < 40; ++m) bw[m] = wp[m];
    }
    const float bias_c = bih[colg] + bhh[colg];

    // ---- prologue: stage x for t=0 ----
    {
        const float* xp = x + ((size_t)(b0 + prow)*T_ + 0)*I_ + pi0;
        f32x4 p0 = *reinterpret_cast<const f32x4*>(xp);
        f32x4 p1 = *reinterpret_cast<const f32x4*>(xp + 4);
        f32x4 p2 = *reinterpret_cast<const f32x4*>(xp + 8);
        f32x4 p3 = *reinterpret_cast<const f32x4*>(xp + 12);
        unsigned int pk[8];
        #pragma unroll
        for (int u = 0; u < 8; ++u) {
            f32x4 src = (u < 2) ? p0 : (u < 4) ? p1 : (u < 6) ? p2 : p3;
            int e = (u & 1) * 2;
            pk[u] = (unsigned int)f2bf(src[e]) | ((unsigned int)f2bf(src[e + 1]) << 16);
        }
        char* xw = reinterpret_cast<char*>(&xlds[0][0]);
        int wb = prow*512 + (tid & 15)*32;
        int sw = (prow & 7) << 4;
        *reinterpret_cast<u32x4*>(xw + ((wb)      ^ sw)) = u32x4{pk[0], pk[1], pk[2], pk[3]};
        *reinterpret_cast<u32x4*>(xw + ((wb + 16) ^ sw)) = u32x4{pk[4], pk[5], pk[6], pk[7]};
    }
    __syncthreads();

    unsigned int* mycnt = cnt + bg * 256;

    for (int t = 0; t < T_; ++t) {
        // 1. issue x loads for t+1 (hide HBM latency under MFMA loop)
        f32x4 px0, px1, px2, px3;
        const bool pf = (t + 1 < T_);
        if (pf) {
            const float* xp = x + ((size_t)(b0 + prow)*T_ + (t + 1))*I_ + pi0;
            px0 = *reinterpret_cast<const f32x4*>(xp);
            px1 = *reinterpret_cast<const f32x4*>(xp + 4);
            px2 = *reinterpret_cast<const f32x4*>(xp + 8);
            px3 = *reinterpret_cast<const f32x4*>(xp + 12);
        }

        // 2. MFMA over this step's K-half (20 chunks x {hi,lo})
        f32x4 aH0 = {0.f,0.f,0.f,0.f}, aH1 = {0.f,0.f,0.f,0.f};
        f32x4 aL0 = {0.f,0.f,0.f,0.f}, aL1 = {0.f,0.f,0.f,0.f};
        const unsigned short* hb = h2 + (size_t)(t & 1) * (B_ * H_);
        if (kh == 0) {
            const unsigned short* hrow = hb + (size_t)(b0 + rowa)*H_ + kgrp*8;
            #pragma unroll
            for (int n = 0; n < 20; ++n) {
                bf16x8 a = *reinterpret_cast<const bf16x8*>(hrow + n*32);
                if ((n & 1) == 0) { aH0 = MF(a, bw[2*n], aH0); aL0 = MF(a, bw[2*n+1], aL0); }
                else              { aH1 = MF(a, bw[2*n], aH1); aL1 = MF(a, bw[2*n+1], aL1); }
            }
        } else {
            const unsigned short* hrow = hb + (size_t)(b0 + rowa)*H_ + 640 + kgrp*8;
            #pragma unroll
            for (int n = 0; n < 12; ++n) {
                bf16x8 a = *reinterpret_cast<const bf16x8*>(hrow + n*32);
                if ((n & 1) == 0) { aH0 = MF(a, bw[2*n], aH0); aL0 = MF(a, bw[2*n+1], aL0); }
                else              { aH1 = MF(a, bw[2*n], aH1); aL1 = MF(a, bw[2*n+1], aL1); }
            }
            const char* xb = reinterpret_cast<const char*>(&xlds[t & 1][0]);
            const int sw = (rowa & 7) << 4;
            #pragma unroll
            for (int n = 12; n < 20; ++n) {
                int off = (rowa*512 + (n - 12)*64 + (kgrp << 4)) ^ sw;
                bf16x8 a = *reinterpret_cast<const bf16x8*>(xb + off);
                if ((n & 1) == 0) { aH0 = MF(a, bw[2*n], aH0); aL0 = MF(a, bw[2*n+1], aL0); }
                else              { aH1 = MF(a, bw[2*n], aH1); aL1 = MF(a, bw[2*n+1], aL1); }
            }
        }
        f32x4 facc = aH0 + aH1 + aL0 + aL1;

        // 3. K-half reduce + epilogue (tanh, store next h)
        if (kh == 1) *reinterpret_cast<f32x4*>(&red[ch][lane][0]) = facc;
        __syncthreads();
        if (kh == 0) {
            f32x4 other = *reinterpret_cast<const f32x4*>(&red[ch][lane][0]);
            unsigned short* hn = h2 + (size_t)((t + 1) & 1) * (B_ * H_);
            float hv[4];
            #pragma unroll
            for (int r = 0; r < 4; ++r) {
                float zz = facc[r] + other[r] + bias_c;
                float az = fabsf(zz);
                float e  = __expf(-2.f * az);
                float th = (1.f - e) / (1.f + e);
                hv[r] = copysignf(th, zz);
            }
            #pragma unroll
            for (int r = 0; r < 4; ++r) {
                int row = b0 + kgrp*4 + r;
                hn[(size_t)row*H_ + colg] = f2bf(hv[r]);
            }
            if (t == T_ - 1) {
                #pragma unroll
                for (int r = 0; r < 4; ++r) {
                    int row = b0 + kgrp*4 + r;
                    outh[(size_t)row*H_ + colg] = hv[r];   // exact fp32 hidden out
                }
            }
        }

        // 4. write x prefetch into other LDS buffer
        if (pf) {
            unsigned int pk[8];
            #pragma unroll
            for (int u = 0; u < 8; ++u) {
                f32x4 src = (u < 2) ? px0 : (u < 4) ? px1 : (u < 6) ? px2 : px3;
                int e = (u & 1) * 2;
                pk[u] = (unsigned int)f2bf(src[e]) | ((unsigned int)f2bf(src[e + 1]) << 16);
            }
            char* xw = reinterpret_cast<char*>(&xlds[(t + 1) & 1][0]);
            int wb = prow*512 + (tid & 15)*32;
            int sw = (prow & 7) << 4;
            *reinterpret_cast<u32x4*>(xw + ((wb)      ^ sw)) = u32x4{pk[0], pk[1], pk[2], pk[3]};
            *reinterpret_cast<u32x4*>(xw + ((wb + 16) ^ sw)) = u32x4{pk[4], pk[5], pk[6], pk[7]};
        }

        // 5. inter-WG barrier among the 32 WGs of this batch group
        __syncthreads();
        if (tid == 0) {
            __hip_atomic_fetch_add(mycnt, 1u, __ATOMIC_RELEASE, __HIP_MEMORY_SCOPE_AGENT);
            const unsigned int target = 32u * (unsigned int)(t + 1);
            while (__hip_atomic_load(mycnt, __ATOMIC_RELAXED, __HIP_MEMORY_SCOPE_AGENT) < target) {}
            (void)__hip_atomic_load(mycnt, __ATOMIC_ACQUIRE, __HIP_MEMORY_SCOPE_AGENT);
        }
        __syncthreads();
    }
}

// ---------------- final fc: out = h_last @ W_fc^T + b_fc (fp32) ----------------
__global__ void k_fc(const float* __restrict__ h, const float* __restrict__ Wfc,
                     const float* __restrict__ bfc, float* __restrict__ out) {
    int bq = blockIdx.x & 7, oq = blockIdx.x >> 3;    // 8 x 16 blocks
    int bl = threadIdx.x & 15, ol = threadIdx.x >> 4;
    int b = bq*16 + bl, o = oq*16 + ol;
    const float* hr = h   + (size_t)b * H_;
    const float* wr = Wfc + (size_t)o * H_;
    float acc = 0.f;
    #pragma unroll 4
    for (int k = 0; k < H_; k += 4) {
        f32x4 hv = *reinterpret_cast<const f32x4*>(hr + k);
        f32x4 wvv = *reinterpret_cast<const f32x4*>(wr + k);
        acc += hv[0]*wvv[0] + hv[1]*wvv[1] + hv[2]*wvv[2] + hv[3]*wvv[3];
    }
    out[(size_t)b * O_ + o] = acc + bfc[o];
}

extern "C" void kernel_launch(void* const* d_in, const int* in_sizes, int n_in,
                              void* d_out, int out_size, void* d_ws, size_t ws_size,
                              hipStream_t stream) {
    const float* x   = (const float*)d_in[0];
    const float* hid = (const float*)d_in[1];
    const float* Wih = (const float*)d_in[2];
    const float* Whh = (const float*)d_in[3];
    const float* bih = (const float*)d_in[4];
    const float* bhh = (const float*)d_in[5];
    const float* Wfc = (const float*)d_in[6];
    const float* bfc = (const float*)d_in[7];
    float* out = (float*)d_out;
    char* ws = (char*)d_ws;

    unsigned short* Wp  = (unsigned short*)(ws);
    unsigned short* h2  = (unsigned short*)(ws + WP_BYTES);
    unsigned int*   cnt = (unsigned int*)(ws + WP_BYTES + H2_BYTES);
    float* outh = out + B_ * O_;   // hidden output region, also h_last fp32

    k_pack<<<1280, 256, 0, stream>>>(Whh, Wih, Wp);
    k_init<<<512, 256, 0, stream>>>(hid, h2, cnt);

    void* args[] = { (void*)&x, (void*)&Wp, (void*)&h2, (void*)&cnt,
                     (void*)&bih, (void*)&bhh, (void*)&outh };
    hipLaunchCooperativeKernel((const void*)k_rnn, dim3(256), dim3(256), args, 0, stream);

    k_fc<<<128, 256, 0, stream>>>(outh, Wfc, bfc, out);
}